// Round 10
// baseline (144.366 us; speedup 1.0000x reference)
//
#include <hip/hip_runtime.h>

#define N_PTS 8192
#define BATCH 2
#define KNN 8
#define NBLK_C 512                 // chamfer: 4 combos x 128 row-blocks (64 rows, 1/lane)
#define NBLK_S 1024                // smooth: 2 batches x 512 groups (16 pts, 4/wave)
#define NBLOCKS (NBLK_C + NBLK_S)  // 1536, role-interleaved by bx%3 (2 S : 1 C)

// packed workspace layout: float4(x,y,z,|p|^2) per point
//  arr 0,1: pc2[b] | arr 2,3: pc1[b]+flow[b] (warped) | arr 4,5: pc1[b]
// total 6*8192*16B = 768 KiB in d_ws
#define ARR_PC2  0
#define ARR_WARP 2
#define ARR_PC1  4

// R9 audit: VALUBusy=88% is the gfx94x SIMD-16 formula on SIMD-32 HW (~2x
// inflated; real ~44%). Static count: ~37M wave-instrs ~= 30us of issue, vs
// 87.6us measured -> kernel is HALF-STALLED on vector memory: every wave
// streamed the full 128KB cand array (1.5GB L2 / 1.57M dwordx4 ~= 40us TA).
// R10: (a) chamfer inverted -- lane owns row, candidates are WAVE-UNIFORM
// s_load (scalar pipe, 16B/access, zero TA); traffic 512MB -> 64MB; shuffle
// reduction eliminated. (b) smooth 4 rows/wave (R4-proven): 1GB -> 512MB.
// VALU held constant (18.3 evals/instr both ways).

// ---------------- helpers ----------------
__device__ __forceinline__ void ce(unsigned &x, unsigned &y) {
    unsigned lo = min(x, y), hi = max(x, y); x = lo; y = hi;
}

__device__ __forceinline__ void insert4(unsigned o[4], unsigned key) {
    unsigned n0 = min(o[0], key);
    unsigned n1 = max(o[0], min(o[1], key));
    unsigned n2 = max(o[1], min(o[2], key));
    unsigned n3 = max(o[2], min(o[3], key));
    o[0]=n0; o[1]=n1; o[2]=n2; o[3]=n3;
}

__device__ __forceinline__ void merge_stage8(unsigned m[8], int d) {
    unsigned p[8], c[8];
    #pragma unroll
    for (int k = 0; k < 8; ++k) p[k] = (unsigned)__shfl_xor((int)m[k], d, 64);
    #pragma unroll
    for (int k = 0; k < 8; ++k) c[k] = min(m[k], p[7-k]);
    ce(c[0],c[4]); ce(c[1],c[5]); ce(c[2],c[6]); ce(c[3],c[7]);
    ce(c[0],c[2]); ce(c[1],c[3]); ce(c[4],c[6]); ce(c[5],c[7]);
    ce(c[0],c[1]); ce(c[2],c[3]); ce(c[4],c[5]); ce(c[6],c[7]);
    #pragma unroll
    for (int k = 0; k < 8; ++k) m[k] = c[k];
}

__device__ __forceinline__ void merge64(unsigned m[8]) {
    merge_stage8(m, 1); merge_stage8(m, 2); merge_stage8(m, 4);
    merge_stage8(m, 8); merge_stage8(m, 16); merge_stage8(m, 32);
}

// ---------------- pack: 6 float4 arrays, one-time warp-add + |p|^2 ----------------
__global__ __launch_bounds__(256) void pack_kernel(
        const float* __restrict__ pc1, const float* __restrict__ pc2,
        const float* __restrict__ flow, float4* __restrict__ ws) {
    const int t = blockIdx.x * 256 + threadIdx.x;   // 0 .. 6*8192-1
    const int arr = t >> 13, i = t & (N_PTS - 1);
    const int bb = arr & 1;
    const size_t base = (size_t)bb * N_PTS * 3 + (size_t)i * 3;
    float x, y, z;
    if (arr < 2)      { x = pc2[base+0];              y = pc2[base+1];              z = pc2[base+2]; }
    else if (arr < 4) { x = pc1[base+0] + flow[base+0];
                        y = pc1[base+1] + flow[base+1];
                        z = pc1[base+2] + flow[base+2]; }
    else              { x = pc1[base+0];              y = pc1[base+1];              z = pc1[base+2]; }
    ws[t] = make_float4(x, y, z, fmaf(x, x, fmaf(y, y, z * z)));
}

// ---------------- mega: role-interleaved C|S blocks ----------------
__global__ __launch_bounds__(256, 4) void mega_kernel(
        const float4* __restrict__ ws, const float* __restrict__ flow,
        float* __restrict__ out) {
    __shared__ float cmin[4][64];   // chamfer slice-combine
    __shared__ float psum[4];       // smooth wave partials
    const int tid = threadIdx.x, bx = blockIdx.x;
    const int lane = tid & 63, wv = tid >> 6;
    const int ri = bx / 3, role = bx % 3;   // ri in [0,512)

    if (role == 2) {
        // ===== role C: chamfer, 64 rows/block (1/lane), uniform-candidate scan =====
        // Lane owns one row; candidates loaded at wave-uniform addresses ->
        // scalar s_load (16B/access through K$, no TA, no L2 1KB bursts).
        // 4 waves split the 8192 candidates into 2048-slices; LDS min-combine.
        const int z = ri >> 7, bb = z & 1, dir = z >> 1;
        const int cb = ri & 127;
        const float4* rows = ws + (size_t)((dir == 0 ? ARR_WARP : ARR_PC2) + bb) * N_PTS;
        const float4* cand = ws + (size_t)((dir == 0 ? ARR_PC2 : ARR_WARP) + bb) * N_PTS;

        float4 q = rows[cb * 64 + lane];         // per-lane row (coalesced)
        const float mx = -2.0f * q.x, my = -2.0f * q.y, mz = -2.0f * q.z;
        const float p2 = q.w;
        float bmin = __builtin_inff();

        // readfirstlane pins the slice base uniform -> LLVM divergence
        // analysis scalarizes cand[j] (tid>>6 alone is not provably uniform)
        const int wvu = __builtin_amdgcn_readfirstlane(wv);
        const int j0 = wvu * 2048;
        #pragma unroll 8
        for (int j = j0; j < j0 + 2048; j += 2) {
            float4 ca = cand[j];                 // uniform -> s_load
            float4 cb4 = cand[j + 1];
            float sa = fmaf(mx, ca.x,  fmaf(my, ca.y,  fmaf(mz, ca.z,  ca.w)));
            float sb = fmaf(mx, cb4.x, fmaf(my, cb4.y, fmaf(mz, cb4.z, cb4.w)));
            bmin = fminf(fminf(bmin, sa), sb);   // folds to v_min3
        }
        cmin[wv][lane] = bmin;
        __syncthreads();
        if (wv == 0) {
            float m = fminf(fminf(cmin[0][lane], cmin[1][lane]),
                            fminf(cmin[2][lane], cmin[3][lane]));
            float val = sqrtf(fmaxf(m + p2, 0.0f));
            #pragma unroll
            for (int d = 1; d < 64; d <<= 1) val += __shfl_xor(val, d, 64);
            if (lane == 0) atomicAdd(out, val * (1.0f / (float)(BATCH * N_PTS)));
        }
    } else {
        // ===== role S: smooth, 16 points/block (4/wave), gated KNN =====
        const int sbx = ri * 2 + role;           // [0, 1024)
        const int b  = sbx >> 9;
        const int sx = sbx & 511;
        const int i0w = sx * 16 + wv * 4;
        const float4* cand = ws + (size_t)(ARR_PC1 + b) * N_PTS;
        const float* F = flow + (size_t)b * N_PTS * 3;

        float mx[4], my[4], mz[4], p2[4], gr[4];
        unsigned thr[4], o[4][4];
        #pragma unroll
        for (int r = 0; r < 4; ++r) {
            float4 q = cand[i0w + r];            // wave-uniform
            mx[r] = -2.0f * q.x; my[r] = -2.0f * q.y; mz[r] = -2.0f * q.z;
            p2[r] = q.w;
            gr[r] = __builtin_inff();
            thr[r] = 0xFFFFFFFFu;
            #pragma unroll
            for (int k = 0; k < 4; ++k) o[r][k] = 0xFFFFFFFFu;
        }

        // tight thr: per-32-half true top-4 via 5-stage butterfly;
        // bound = max of the two halves' 4th keys (8 real keys >= true 8th)
        auto update_thr = [&]() {
            #pragma unroll
            for (int r = 0; r < 4; ++r) {
                unsigned m0 = o[r][0], m1 = o[r][1], m2 = o[r][2], m3 = o[r][3];
                #pragma unroll
                for (int d = 1; d <= 16; d <<= 1) {
                    unsigned q0 = (unsigned)__shfl_xor((int)m0, d, 64);
                    unsigned q1 = (unsigned)__shfl_xor((int)m1, d, 64);
                    unsigned q2 = (unsigned)__shfl_xor((int)m2, d, 64);
                    unsigned q3 = (unsigned)__shfl_xor((int)m3, d, 64);
                    unsigned c0 = min(m0, q3), c1 = min(m1, q2);
                    unsigned c2 = min(m2, q1), c3 = min(m3, q0);
                    ce(c0, c2); ce(c1, c3); ce(c0, c1); ce(c2, c3);
                    m0 = c0; m1 = c1; m2 = c2; m3 = c3;
                }
                unsigned bound = max(m3, (unsigned)__shfl_xor((int)m3, 32, 64));
                thr[r] = min(thr[r], bound);
                // +2 truncation-buckets slack: gate passes superset of key<=thr
                float thr_up = __uint_as_float((thr[r] & 0xFFFFE000u) + 0x4000u);
                gr[r] = thr_up - p2[r];
            }
        };

        // paired slabs: 2 loads in flight, ONE uniform branch per row per 128 cands
        auto gated_span = [&](int j0, int j1) {
            #pragma unroll 2
            for (int j = j0; j < j1; j += 128) {
                float4 qa = cand[j + lane];
                float4 qb = cand[j + 64 + lane];
                int ja = j + lane, jb = j + 64 + lane;
                float sa[4], sb[4];
                #pragma unroll
                for (int r = 0; r < 4; ++r) {
                    sa[r] = fmaf(mx[r], qa.x, fmaf(my[r], qa.y, fmaf(mz[r], qa.z, qa.w)));
                    sb[r] = fmaf(mx[r], qb.x, fmaf(my[r], qb.y, fmaf(mz[r], qb.z, qb.w)));
                }
                #pragma unroll
                for (int r = 0; r < 4; ++r) {
                    if (__any(fminf(sa[r], sb[r]) <= gr[r])) {
                        float da = fmaxf(sa[r] + p2[r], 0.0f);
                        unsigned ka = (__float_as_uint(da) & 0xFFFFE000u) | (unsigned)ja;
                        ka = (ja == i0w + r) ? 0xFFFFFFFFu : ka;
                        insert4(o[r], ka);
                        float db = fmaxf(sb[r] + p2[r], 0.0f);
                        unsigned kb = (__float_as_uint(db) & 0xFFFFE000u) | (unsigned)jb;
                        kb = (jb == i0w + r) ? 0xFFFFFFFFu : kb;
                        insert4(o[r], kb);
                    }
                }
            }
        };

        // chunk 0 (1024 cands) unconditional sample, then gated spans;
        // thr refresh after 1024 / 2048 / 4096 (proven schedule)
        #pragma unroll 2
        for (int j = 0; j < 1024; j += 128) {
            float4 qa = cand[j + lane];
            float4 qb = cand[j + 64 + lane];
            int ja = j + lane, jb = j + 64 + lane;
            #pragma unroll
            for (int r = 0; r < 4; ++r) {
                float sa = fmaf(mx[r], qa.x, fmaf(my[r], qa.y, fmaf(mz[r], qa.z, qa.w)));
                float da = fmaxf(sa + p2[r], 0.0f);
                unsigned ka = (__float_as_uint(da) & 0xFFFFE000u) | (unsigned)ja;
                ka = (ja == i0w + r) ? 0xFFFFFFFFu : ka;
                insert4(o[r], ka);
                float sb = fmaf(mx[r], qb.x, fmaf(my[r], qb.y, fmaf(mz[r], qb.z, qb.w)));
                float db = fmaxf(sb + p2[r], 0.0f);
                unsigned kb = (__float_as_uint(db) & 0xFFFFE000u) | (unsigned)jb;
                kb = (jb == i0w + r) ? 0xFFFFFFFFu : kb;
                insert4(o[r], kb);
            }
        }
        update_thr();
        gated_span(1024, 2048); update_thr();
        gated_span(2048, 4096); update_thr();
        gated_span(4096, N_PTS);

        // final per-point top-8 + epilogue; sel = (point, k) over 32 slots,
        // lane dup x2 -> scale /2 (0.25 total with W=0.5)
        const int sel = lane & 31;
        const int pr = sel >> 3, kk = sel & 7;
        unsigned mykey = 0xFFFFFFFFu;
        #pragma unroll
        for (int r = 0; r < 4; ++r) {
            unsigned m[8] = {o[r][0], o[r][1], o[r][2], o[r][3],
                             0xFFFFFFFFu, 0xFFFFFFFFu, 0xFFFFFFFFu, 0xFFFFFFFFu};
            merge64(m);
            if (pr == r) {
                unsigned k2 = m[0];
                #pragma unroll
                for (int t = 1; t < 8; ++t) k2 = (kk == t) ? m[t] : k2;
                mykey = k2;
            }
        }
        const int i = i0w + pr;
        const int j = (int)(mykey & (N_PTS - 1));
        float dx = F[i*3+0] - F[j*3+0];
        float dy = F[i*3+1] - F[j*3+1];
        float dz = F[i*3+2] - F[j*3+2];
        float sv = sqrtf(fmaf(dx, dx, fmaf(dy, dy, dz * dz)));
        #pragma unroll
        for (int d = 1; d < 64; d <<= 1) sv += __shfl_xor(sv, d, 64);
        if (lane == 0) psum[wv] = sv;
        __syncthreads();

        if (tid == 0) {
            float sm = psum[0] + psum[1] + psum[2] + psum[3];
            // smooth: W=0.5, /2 lane dup -> 0.25
            atomicAdd(out, sm * (0.25f / ((float)BATCH * N_PTS * KNN)));
        }
    }
}

extern "C" void kernel_launch(void* const* d_in, const int* in_sizes, int n_in,
                              void* d_out, int out_size, void* d_ws, size_t ws_size,
                              hipStream_t stream) {
    const float* pc1  = (const float*)d_in[0];
    const float* pc2  = (const float*)d_in[1];
    const float* flow = (const float*)d_in[2];
    float* out = (float*)d_out;
    float4* ws4 = (float4*)d_ws;   // needs 6*8192*16B = 768 KiB

    pack_kernel<<<dim3(6 * N_PTS / 256), 256, 0, stream>>>(pc1, pc2, flow, ws4);
    mega_kernel<<<dim3(NBLOCKS), 256, 0, stream>>>(ws4, flow, out);
}